// Round 12
// baseline (286.519 us; speedup 1.0000x reference)
//
#include <hip/hip_runtime.h>
#include <hip/hip_bf16.h>
#include <cstdint>

// Problem constants: B=4, N=1024, F=1024, H=16, D=64, S=2N=2048.
typedef __hip_bfloat16 bf16;
typedef __attribute__((ext_vector_type(8))) short short8;   // 8 x bf16 (4 VGPRs)
typedef __attribute__((ext_vector_type(4))) short short4v;  // 4 x bf16
typedef __attribute__((ext_vector_type(4))) float f32x4;
typedef __attribute__((ext_vector_type(2))) unsigned int uint2v;

#define MFMA16(a, b, c) __builtin_amdgcn_mfma_f32_16x16x32_bf16((a), (b), (c), 0, 0, 0)

__device__ __forceinline__ void gl2lds16(const void* g, void* l) {
  __builtin_amdgcn_global_load_lds(
      (const __attribute__((address_space(1))) unsigned int*)g,
      (__attribute__((address_space(3))) unsigned int*)l,
      16, 0, 0);
}

// pack two f32 -> bf16x2 in ONE VALU op (RNE).
__device__ __forceinline__ unsigned int pkcvt(float a, float b) {
  unsigned int r;
  asm("v_cvt_pk_bf16_f32 %0, %1, %2" : "=v"(r) : "v"(a), "v"(b));
  return r;
}

__device__ __forceinline__ float b2f(unsigned short u) {
  union { unsigned u; float f; } x;
  x.u = ((unsigned)u) << 16;
  return x.f;
}

__device__ __forceinline__ uint2v plswap32(unsigned a, unsigned b) {
#if __has_builtin(__builtin_amdgcn_permlane32_swap)
  return __builtin_amdgcn_permlane32_swap(a, b, false, false);
#else
  const unsigned ax = __shfl_xor((int)a, 32), bx = __shfl_xor((int)b, 32);
  const bool hi = (threadIdx.x & 32) != 0;
  uint2v r;
  r[0] = hi ? bx : a;
  r[1] = hi ? b : ax;
  return r;
#endif
}

__device__ __forceinline__ uint2v plswap16(unsigned a, unsigned b) {
#if __has_builtin(__builtin_amdgcn_permlane16_swap)
  return __builtin_amdgcn_permlane16_swap(a, b, false, false);
#else
  const unsigned ax = __shfl_xor((int)a, 16), bx = __shfl_xor((int)b, 16);
  const bool hi = (threadIdx.x & 16) != 0;
  uint2v r;
  r[0] = hi ? bx : a;
  r[1] = hi ? b : ax;
  return r;
#endif
}

template <int V> struct IC { static constexpr int value = V; };

// ---------------------------------------------------------------------------
// v10 GEMM (best measured). BK=64, 128x128, 4 waves, both-sides XOR swizzle.
// REMAP=1: output row r (0..4095) -> qkv row (r>>10)*2048 + 1024 + (r&1023).
// ---------------------------------------------------------------------------
template <int WRITE_BF16, int REMAP>
__global__ __launch_bounds__(256) void gemm_bt(
    const bf16* __restrict__ A, const bf16* __restrict__ Bt,
    const float* __restrict__ bias, bf16* __restrict__ outb,
    float* __restrict__ outf, int M, int N, int K) {
  __shared__ bf16 sA[128 * 64];
  __shared__ bf16 sB[128 * 64];
  const int tid = threadIdx.x, w = tid >> 6, lane = tid & 63;
  const int n16 = lane & 15, quad = lane >> 4;
  const int mBase = blockIdx.y * 128, nBase = blockIdx.x * 128;
  const int wr = w >> 1, wc = w & 1;

  f32x4 acc[4][4];
#pragma unroll
  for (int mi = 0; mi < 4; mi++)
#pragma unroll
    for (int ni = 0; ni < 4; ni++) acc[mi][ni] = (f32x4){0.f, 0.f, 0.f, 0.f};

  const bf16* ag[4];
  const bf16* bg[4];
#pragma unroll
  for (int i = 0; i < 4; i++) {
    const int e = (i * 256 + tid) * 8;
    const int row = e >> 6, c0 = e & 63;
    const int col = c0 ^ ((row & 7) << 3);
    ag[i] = A + (size_t)(mBase + row) * K + col;
    bg[i] = Bt + (size_t)(nBase + row) * K + col;
  }
  const int u = (quad * 16) ^ ((n16 & 7) << 4);
  const int a0 = (wr * 64 + n16) * 128 + u;
  const int b0 = (wc * 64 + n16) * 128 + u;
  const char* const sAB = (const char*)sA;
  const char* const sBB = (const char*)sB;

  for (int k0 = 0; k0 < K; k0 += 64) {
    __syncthreads();
#pragma unroll
    for (int i = 0; i < 4; i++) {
      gl2lds16(ag[i] + k0, sA + i * 2048 + w * 512);
      gl2lds16(bg[i] + k0, sB + i * 2048 + w * 512);
    }
    __syncthreads();

#pragma unroll
    for (int kk = 0; kk < 2; kk++) {
      short8 af[4], bfg[4];
#pragma unroll
      for (int t = 0; t < 4; t++) {
        af[t] = *(const short8*)(sAB + (a0 ^ (kk << 6)) + t * 2048);
        bfg[t] = *(const short8*)(sBB + (b0 ^ (kk << 6)) + t * 2048);
      }
#pragma unroll
      for (int mi = 0; mi < 4; mi++)
#pragma unroll
        for (int ni = 0; ni < 4; ni++)
          acc[mi][ni] = MFMA16(af[mi], bfg[ni], acc[mi][ni]);
    }
  }

#pragma unroll
  for (int mi = 0; mi < 4; mi++)
#pragma unroll
    for (int ni = 0; ni < 4; ni++)
#pragma unroll
      for (int r = 0; r < 4; r++) {
        const int row = mBase + wr * 64 + mi * 16 + quad * 4 + r;
        const int col = nBase + wc * 64 + ni * 16 + n16;
        const size_t orow =
            REMAP ? (size_t)((row >> 10) * 2048 + 1024 + (row & 1023))
                  : (size_t)row;
        const float v = acc[mi][ni][r] + bias[col];
        if (WRITE_BF16)
          outb[orow * N + col] = __float2bfloat16(v);
        else
          outf[orow * N + col] = v;
      }
}

// ---------------------------------------------------------------------------
// Flash attention v16 = v15 + LPT block reorder. All blocks iterate only the
// 16 feature-key tiles; scene-key mass handled by exact collapse corrections.
// v15 counters: occupancy 10.5% (cap 37.5%) -> long feature-only tail because
// light scene blocks (no K staging / no QK^T) interleave with heavy feature
// blocks and finish early. Fix: dispatch all 512 HEAVY feature blocks first
// (blockIdx < 512), scene blocks backfill the tail (LPT scheduling).
// ---------------------------------------------------------------------------
__global__ __launch_bounds__(256) void flash_kernel(
    const bf16* __restrict__ qkv, const float* __restrict__ relf,
    bf16* __restrict__ attn, const float* __restrict__ lR1,
    const float* __restrict__ ssf, const float* __restrict__ ssc) {
  constexpr int S = 2048, R3 = 3072;
  __shared__ __align__(16) char smem[32768];
  bf16* const sK = (bf16*)smem;       // [buf][key][64] 128 B rows, XOR-swizzled
  char* const sVtB = smem + 16384;    // [buf][d][key] 128 B rows, XOR-swizzled

  const int tid = threadIdx.x, w = tid >> 6, lane = tid & 63;
  const int n16 = lane & 15, quad = lane >> 4;
  // LPT: feature-q blocks (qt>=8, heavy) first, scene-q blocks last.
  int qt, bh;
  {
    const int li = blockIdx.x;
    if (li < 512) { bh = li >> 3; qt = 8 + (li & 7); }
    else          { const int m = li - 512; bh = m >> 3; qt = m & 7; }
  }
  const int h = bh & 15, b = bh >> 4;
  const int qb = qt * 128 + w * 32;
  const size_t rowbase = (size_t)b * S;
  const bool isFeat = (qt >= 8);
  const size_t krow0 = rowbase + 1024;  // feature keys for BOTH classes
  const float SC = 0.125f * 1.44269504f;
  const size_t TADV = (size_t)64 * R3;

  short8 qf[2][2];
  if (isFeat) {
#pragma unroll
    for (int mi = 0; mi < 2; mi++) {
      const bf16* qp = qkv + (rowbase + qb + mi * 16 + n16) * R3 + h * 64;
#pragma unroll
      for (int c = 0; c < 2; c++)
        qf[mi][c] = *(const short8*)(qp + c * 32 + quad * 8);
    }
  }

  f32x4 ot[4][2];
#pragma unroll
  for (int nc = 0; nc < 4; nc++)
#pragma unroll
    for (int mi = 0; mi < 2; mi++) ot[nc][mi] = (f32x4){0.f, 0.f, 0.f, 0.f};
  float l_lane[2] = {0.f, 0.f};

  const bf16* kg0;
  const bf16* kg1;
  {
    const int e0 = tid * 8;
    const int e1i = (256 + tid) * 8;
    const int k0r = e0 >> 6, c00 = e0 & 63;
    const int k1r = e1i >> 6, c01 = e1i & 63;
    kg0 = qkv + (krow0 + k0r) * R3 + 1024 + h * 64 + (c00 ^ ((k0r & 7) << 3));
    kg1 = qkv + (krow0 + k1r) * R3 + 1024 + h * 64 + (c01 ^ ((k1r & 7) << 3));
  }
  const int kldsoff = w * 512;

  const int kb0 = n16 * 128 + ((quad * 16) ^ ((n16 & 7) << 4));
  const int kb1 = kb0 ^ 64;
  const char* const sKB = (const char*)sK;

  const int kp = lane & 31;
  const int vd0 = w * 16 + (lane >> 5) * 8;
  const int kp4 = kp * 4;
  const bf16* vp = qkv + (krow0 + 2 * kp) * R3 + 2048 + h * 64 + vd0;

  const int vb0 = 128 * n16 + ((16 * quad) ^ ((n16 & 7) << 4));
  const int vb1 = vb0 ^ 64;

  // scene path: precomputed SC*(q_scene . k_feat) per key; lane covers quad*4..+3
  const float* ssp = ssf + (size_t)bh * 1024 + quad * 4;

  short8 v0, v1;
  auto vstage = [&](int bufbyte) {
    const unsigned* a1 = (const unsigned*)&v1;
    const unsigned* a0 = (const unsigned*)&v0;
#pragma unroll
    for (int j = 0; j < 4; j++) {
      const unsigned lo = __builtin_amdgcn_perm(a1[j], a0[j], 0x05040100u);
      const unsigned hi = __builtin_amdgcn_perm(a1[j], a0[j], 0x07060302u);
      *(unsigned*)(sVtB + bufbyte + 128 * (vd0 + 2 * j) + (kp4 ^ ((2 * j) << 4))) = lo;
      *(unsigned*)(sVtB + bufbyte + 128 * (vd0 + 2 * j + 1) + (kp4 ^ ((2 * j + 1) << 4))) = hi;
    }
  };

  if (isFeat) {
    gl2lds16(kg0, sK + kldsoff);
    gl2lds16(kg1, sK + kldsoff + 2048);
    kg0 += TADV;
    kg1 += TADV;
  }

  v0 = *(const short8*)vp;
  v1 = *(const short8*)(vp + R3);
  vstage(0);
  vp += TADV;
  v0 = *(const short8*)vp;
  v1 = *(const short8*)(vp + R3);
  vp += TADV;

  float4 rv[8];
  const float4* rpA = (const float4*)relf +
                      (size_t)(qt * 32 + 16) * 2048 + w * 512 + lane;
  const float4* rpB = rpA + 256;
#pragma unroll
  for (int j = 0; j < 4; j++) {
    rv[j] = rpA[j * 64];
    rv[4 + j] = rpB[j * 64];
  }
  rpA += 2048;
  rpB += 2048;

  auto step = [&](auto curc, auto scnc, bool dodma, bool dovpf) {
    constexpr int CUR = decltype(curc)::value;
    constexpr int NXT = CUR ^ 1;
    constexpr int SCN = decltype(scnc)::value;
    __syncthreads();

    if (dodma) {
      if constexpr (!SCN) {
        gl2lds16(kg0, sK + NXT * 4096 + kldsoff);
        kg0 += TADV;
        gl2lds16(kg1, sK + NXT * 4096 + kldsoff + 2048);
        kg1 += TADV;
      }
      vstage(NXT * 8192);
    }

#pragma unroll
    for (int kc = 0; kc < 2; kc++) {
      f32x4 st[2][2];
      float4 ssq[2];
      if constexpr (SCN) {
        ssq[0] = *(const float4*)(ssp + (2 * kc + 0) * 16);
        ssq[1] = *(const float4*)(ssp + (2 * kc + 1) * 16);
      } else {
#pragma unroll
        for (int t2 = 0; t2 < 2; t2++) {
          const int kt4 = 2 * kc + t2;
          short8 kf[2];
          kf[0] = *(const short8*)(sKB + CUR * 8192 + kt4 * 2048 + kb0);
          kf[1] = *(const short8*)(sKB + CUR * 8192 + kt4 * 2048 + kb1);
#pragma unroll
          for (int mi = 0; mi < 2; mi++) {
            f32x4 z = (f32x4){0.f, 0.f, 0.f, 0.f};
            z = MFMA16(kf[0], qf[mi][0], z);
            z = MFMA16(kf[1], qf[mi][1], z);
            st[t2][mi] = z;
          }
        }
      }
      if (kc == 0 && dovpf) {
        v0 = *(const short8*)vp;
        v1 = *(const short8*)(vp + R3);
        vp += TADV;
      }
      short8 pb[2];
#pragma unroll
      for (int mi = 0; mi < 2; mi++) {
        float acc = 0.f;
        unsigned d[2][2];
#pragma unroll
        for (int t2 = 0; t2 < 2; t2++) {
          const float4 rr = rv[mi * 4 + 2 * kc + t2];
          float p0, p1, p2, p3;
          if constexpr (SCN) {
            p0 = __builtin_amdgcn_exp2f(ssq[t2].x + rr.x);
            p1 = __builtin_amdgcn_exp2f(ssq[t2].y + rr.y);
            p2 = __builtin_amdgcn_exp2f(ssq[t2].z + rr.z);
            p3 = __builtin_amdgcn_exp2f(ssq[t2].w + rr.w);
          } else {
            p0 = __builtin_amdgcn_exp2f(fmaf(st[t2][mi][0], SC, rr.x));
            p1 = __builtin_amdgcn_exp2f(fmaf(st[t2][mi][1], SC, rr.y));
            p2 = __builtin_amdgcn_exp2f(fmaf(st[t2][mi][2], SC, rr.z));
            p3 = __builtin_amdgcn_exp2f(fmaf(st[t2][mi][3], SC, rr.w));
          }
          acc += (p0 + p1) + (p2 + p3);
          d[t2][0] = pkcvt(p0, p1);
          d[t2][1] = pkcvt(p2, p3);
        }
        l_lane[mi] += acc;
        const uint2v e0 = plswap32(d[0][0], d[1][0]);
        const uint2v e1 = plswap32(d[0][1], d[1][1]);
        const uint2v f0 = plswap16(e0[0], e0[1]);
        const uint2v f1 = plswap16(e1[0], e1[1]);
        union { short8 s; unsigned u[4]; } P;
        P.u[0] = f0[0]; P.u[1] = f1[0]; P.u[2] = f0[1]; P.u[3] = f1[1];
        pb[mi] = P.s;
      }
      if (kc == 1 && dodma) {
#pragma unroll
        for (int j = 0; j < 4; j++) {
          rv[j] = rpA[j * 64];
          rv[4 + j] = rpB[j * 64];
        }
        rpA += 2048;
        rpB += 2048;
      }
      short8 va[4];
#pragma unroll
      for (int nc = 0; nc < 4; nc++)
        va[nc] = *(const short8*)(sVtB + CUR * 8192 + 2048 * nc +
                                  (kc ? vb1 : vb0));
#pragma unroll
      for (int nc = 0; nc < 4; nc++)
#pragma unroll
        for (int mi = 0; mi < 2; mi++)
          ot[nc][mi] = MFMA16(va[nc], pb[mi], ot[nc][mi]);
    }
    if constexpr (SCN) ssp += 64;
  };

  if (isFeat) {
#pragma unroll 1
    for (int t = 0; t < 8; t++) {
      const bool g = (t < 7);
      step(IC<0>{}, IC<0>{}, true, g);
      step(IC<1>{}, IC<0>{}, g, g);
    }
  } else {
#pragma unroll 1
    for (int t = 0; t < 8; t++) {
      const bool g = (t < 7);
      step(IC<0>{}, IC<1>{}, true, g);
      step(IC<1>{}, IC<1>{}, g, g);
    }
  }

  // ---- scene-key collapse correction (exact, f32) — ALL blocks
  {
    float e1v[2];
    if (isFeat) {
      const bf16* kscp = qkv + rowbase * R3 + 1024 + h * 64 + quad * 8;
      const short8 ks0 = *(const short8*)(kscp);
      const short8 ks1 = *(const short8*)(kscp + 32);
#pragma unroll
      for (int mi = 0; mi < 2; mi++) {
        float ss = 0.f;
#pragma unroll
        for (int j = 0; j < 8; j++) {
          ss = fmaf(b2f((unsigned short)qf[mi][0][j]), b2f((unsigned short)ks0[j]), ss);
          ss = fmaf(b2f((unsigned short)qf[mi][1][j]), b2f((unsigned short)ks1[j]), ss);
        }
        ss += __shfl_xor(ss, 16);
        ss += __shfl_xor(ss, 32);
        const float lr = lR1[qb + mi * 16 + n16];
        e1v[mi] = __builtin_amdgcn_exp2f(fmaf(ss, SC, lr));
        if (quad == 0) l_lane[mi] += e1v[mi];
      }
    } else {
      const float sscv = ssc[bh];  // SC * (q_scene . k_scene)
#pragma unroll
      for (int mi = 0; mi < 2; mi++) {
        const float lr = lR1[qb + mi * 16 + n16];
        e1v[mi] = __builtin_amdgcn_exp2f(sscv + lr);
        if (quad == 0) l_lane[mi] += e1v[mi];
      }
    }
    const bf16* vscp = qkv + rowbase * R3 + 2048 + h * 64;
#pragma unroll
    for (int nc = 0; nc < 4; nc++) {
      const int d0 = nc * 16 + quad * 4;
      const uint2 vv = *(const uint2*)(vscp + d0);
      const float w0 = b2f((unsigned short)(vv.x & 0xffff));
      const float w1 = b2f((unsigned short)(vv.x >> 16));
      const float w2 = b2f((unsigned short)(vv.y & 0xffff));
      const float w3 = b2f((unsigned short)(vv.y >> 16));
#pragma unroll
      for (int mi = 0; mi < 2; mi++) {
        ot[nc][mi][0] = fmaf(e1v[mi], w0, ot[nc][mi][0]);
        ot[nc][mi][1] = fmaf(e1v[mi], w1, ot[nc][mi][1]);
        ot[nc][mi][2] = fmaf(e1v[mi], w2, ot[nc][mi][2]);
        ot[nc][mi][3] = fmaf(e1v[mi], w3, ot[nc][mi][3]);
      }
    }
  }

  float inv[2];
#pragma unroll
  for (int mi = 0; mi < 2; mi++) {
    float l = l_lane[mi];
    l += __shfl_xor(l, 16);
    l += __shfl_xor(l, 32);
    inv[mi] = 1.0f / l;
  }
  __syncthreads();
  bf16* const sEp = (bf16*)smem + w * (32 * 72);
#pragma unroll
  for (int mi = 0; mi < 2; mi++)
#pragma unroll
    for (int nc = 0; nc < 4; nc++) {
      uint2 pk;
      pk.x = pkcvt(ot[nc][mi][0] * inv[mi], ot[nc][mi][1] * inv[mi]);
      pk.y = pkcvt(ot[nc][mi][2] * inv[mi], ot[nc][mi][3] * inv[mi]);
      *(uint2*)(&sEp[(mi * 16 + n16) * 72 + nc * 16 + quad * 4]) = pk;
    }
#pragma unroll
  for (int t = 0; t < 4; t++) {
    const int row = t * 8 + (lane >> 3);
    const int dcol = (lane & 7) * 8;
    const short8 vrow = *(const short8*)(&sEp[row * 72 + dcol]);
    *(short8*)(attn + (rowbase + qb + row) * 1024 + h * 64 + dcol) = vrow;
  }
}

// ---------------------------------------------------------------------------
// prep: weight cast + bias concat + xF build (FEATURE rows only: 4096x1024)
// ---------------------------------------------------------------------------
__global__ void prep_main(const float* __restrict__ fm, const float* __restrict__ Wq,
                          const float* __restrict__ Wk, const float* __restrict__ Wv,
                          const float* __restrict__ Wo, const float* __restrict__ bq,
                          const float* __restrict__ bk, const float* __restrict__ bv,
                          bf16* __restrict__ wW, bf16* __restrict__ wWo,
                          float* __restrict__ bC, bf16* __restrict__ x) {
  const int blk = blockIdx.x;
  if (blk < 4096) {
    const int sel = blk >> 10;
    const int i = (((blk & 1023) * 256) + threadIdx.x) * 4;
    const float* src = (sel == 0) ? Wq : (sel == 1) ? Wk : (sel == 2) ? Wv : Wo;
    bf16* dst = (sel < 3) ? (wW + ((size_t)sel << 20) + i) : (wWo + i);
    const float4 v = *(const float4*)(src + i);
    dst[0] = __float2bfloat16(v.x);
    dst[1] = __float2bfloat16(v.y);
    dst[2] = __float2bfloat16(v.z);
    dst[3] = __float2bfloat16(v.w);
    if (blk == 0) {
      for (int z = threadIdx.x; z < 3072; z += 256)
        bC[z] = (z < 1024) ? bq[z] : (z < 2048) ? bk[z - 1024] : bv[z - 2048];
    }
  } else {
    const size_t i = ((size_t)(blk - 4096) * 256 + threadIdx.x) * 4;
    const float4 v = *(const float4*)(fm + i);
    bf16* d = x + i;
    d[0] = __float2bfloat16(v.x);
    d[1] = __float2bfloat16(v.y);
    d[2] = __float2bfloat16(v.z);
    d[3] = __float2bfloat16(v.w);
  }
}

// scene QKV: sqv[b][j] = bf16( bC[j] + sum_d bf16(scene[b][d]) * wW[j][d] )
// ALSO writes scene row 0 of qkv (k_scene / v_scene for the corrections).
__global__ void scene_qkv(const float* __restrict__ scene,
                          const bf16* __restrict__ wW,
                          const float* __restrict__ bC, bf16* __restrict__ sqv,
                          bf16* __restrict__ qkv) {
  const int tid = threadIdx.x;
  const int p = blockIdx.x * 16 + (tid >> 4);  // 0..12287
  const int i16 = tid & 15;
  const int b = p / 3072, j = p % 3072;
  const bf16* wr = wW + (size_t)j * 1024 + i16 * 64;
  const float* sr = scene + (size_t)b * 1024 + i16 * 64;
  float s = 0.f;
#pragma unroll
  for (int t = 0; t < 8; t++) {
    const short8 wv = *(const short8*)(wr + t * 8);
    const float4 x0 = *(const float4*)(sr + t * 8);
    const float4 x1 = *(const float4*)(sr + t * 8 + 4);
    const float xs[8] = {x0.x, x0.y, x0.z, x0.w, x1.x, x1.y, x1.z, x1.w};
#pragma unroll
    for (int e = 0; e < 8; e++) {
      const float xb = __bfloat162float(__float2bfloat16(xs[e]));
      s = fmaf(b2f((unsigned short)wv[e]), xb, s);
    }
  }
  s += __shfl_xor(s, 1);
  s += __shfl_xor(s, 2);
  s += __shfl_xor(s, 4);
  s += __shfl_xor(s, 8);
  if (i16 == 0) {
    const bf16 val = __float2bfloat16(s + bC[j]);
    sqv[(size_t)b * 3072 + j] = val;
    qkv[(size_t)b * 2048 * 3072 + j] = val;  // scene row 0 of batch b
  }
}

// ssf[bh][k] = SC * dot(q_scene[b,h], K_feat[b,h,k])  (k<1024), and
// ss_sc[bh] = SC * dot(q_scene, k_scene). 16 lanes per dot, 4 d's per lane.
__global__ void sscomp(const bf16* __restrict__ qkv, const bf16* __restrict__ sqv,
                       float* __restrict__ ssf, float* __restrict__ ss_sc) {
  const int tid = threadIdx.x;
  const int g = blockIdx.x * 16 + (tid >> 4);  // 0..65599
  const int i16 = tid & 15;
  const float SC = 0.125f * 1.44269504f;
  const bf16* kr;
  const bf16* qr;
  int bh;
  if (g < 65536) {
    bh = g >> 10;
    const int k = g & 1023;
    const int b = bh >> 4, h = bh & 15;
    kr = qkv + ((size_t)(b * 2048 + 1024 + k)) * 3072 + 1024 + h * 64 + i16 * 4;
    qr = sqv + (size_t)b * 3072 + h * 64 + i16 * 4;
  } else {
    bh = g - 65536;  // 0..63
    const int b = bh >> 4, h = bh & 15;
    kr = sqv + (size_t)b * 3072 + 1024 + h * 64 + i16 * 4;
    qr = sqv + (size_t)b * 3072 + h * 64 + i16 * 4;
  }
  const short4v kv = *(const short4v*)kr;
  const short4v qv = *(const short4v*)qr;
  float s = 0.f;
#pragma unroll
  for (int e = 0; e < 4; e++)
    s = fmaf(b2f((unsigned short)kv[e]), b2f((unsigned short)qv[e]), s);
  s += __shfl_xor(s, 1);
  s += __shfl_xor(s, 2);
  s += __shfl_xor(s, 4);
  s += __shfl_xor(s, 8);
  if (i16 == 0) {
    if (g < 65536) ssf[g] = s * SC;
    else ss_sc[bh] = s * SC;
  }
}

// Fused rel prep: one block per q row (0..2047). Reads the row ONCE:
//   scene half (k<1024)   -> lR1[q] = log2 sum e^rel
//   feature half (k>=1024)-> relf fragment-ordered (x log2e)
// (v15 read rel twice: prep_rel 8MB + prep_r1 16MB.)
__global__ void prep_relr1(const float* __restrict__ rel, float* __restrict__ relf,
                           float* __restrict__ lR1) {
  __shared__ float red[4];
  const int q = blockIdx.x;
  const int t = threadIdx.x;
  const float L2E = 1.44269504f;
  // scene half: k = 4t .. 4t+3
  const float4 vs = *(const float4*)(rel + (size_t)q * 2048 + t * 4);
  float s = __builtin_amdgcn_exp2f(vs.x * L2E) + __builtin_amdgcn_exp2f(vs.y * L2E) +
            __builtin_amdgcn_exp2f(vs.z * L2E) + __builtin_amdgcn_exp2f(vs.w * L2E);
  s += __shfl_xor(s, 1);
  s += __shfl_xor(s, 2);
  s += __shfl_xor(s, 4);
  s += __shfl_xor(s, 8);
  s += __shfl_xor(s, 16);
  s += __shfl_xor(s, 32);
  if ((t & 63) == 0) red[t >> 6] = s;
  // feature half: key = 1024 + ktL*64 + kt4*16 + quad*4, thread t covers one float4
  const int ktL = t >> 4;             // 0..15
  const int sfr = t & 15;             // kt4*4 + quad
  const int kt4 = sfr >> 2, quad = sfr & 3;
  const int key = 1024 + ktL * 64 + kt4 * 16 + quad * 4;
  float4 vf = *(const float4*)(rel + (size_t)q * 2048 + key);
  vf.x *= L2E; vf.y *= L2E; vf.z *= L2E; vf.w *= L2E;
  const int qt = q >> 7, w = (q >> 5) & 3, mi = (q >> 4) & 1, n16 = q & 15;
  const int widx = (qt << 16) + ((16 + ktL) << 11) + (w << 9) +
                   ((mi * 4 + kt4) << 6) + (quad * 16 + n16);
  ((float4*)relf)[widx] = vf;
  __syncthreads();
  if (t == 0)
    lR1[q] = __builtin_amdgcn_logf((red[0] + red[1]) + (red[2] + red[3]));
}

// ---------------------------------------------------------------------------
extern "C" void kernel_launch(void* const* d_in, const int* in_sizes, int n_in,
                              void* d_out, int out_size, void* d_ws,
                              size_t ws_size, hipStream_t stream) {
  const float* fm    = (const float*)d_in[0];
  const float* scene = (const float*)d_in[1];
  const float* rel   = (const float*)d_in[2];
  const float* Wq    = (const float*)d_in[3];
  const float* bq    = (const float*)d_in[4];
  const float* Wk    = (const float*)d_in[5];
  const float* bk    = (const float*)d_in[6];
  const float* Wv    = (const float*)d_in[7];
  const float* bv    = (const float*)d_in[8];
  const float* Wo    = (const float*)d_in[9];
  const float* bo    = (const float*)d_in[10];
  float* out = (float*)d_out;

  char* ws = (char*)d_ws;
  bf16* x    = (bf16*)(ws);                          // 8 MB   [4096,1024] feature rows
  float* relf = (float*)(ws);                        // 16 MB  (aliases x; x dead after QKV)
  bf16* qkv  = (bf16*)(ws + (16u << 20));            // 48 MB  [8192,3072]
  bf16* attn = (bf16*)(ws + (64u << 20));            // 16 MB  [8192,1024]
  bf16* wW   = (bf16*)(ws + (80u << 20));            // 6 MB   [3072,1024]
  bf16* wWo  = (bf16*)(ws + (86u << 20));            // 2 MB   [1024,1024]
  float* bC  = (float*)(ws + (88u << 20));           // 12 KB
  float* lR1 = (float*)(ws + (88u << 20) + 16384);   // 8 KB   [2048]
  bf16* sqv  = (bf16*)(ws + (88u << 20) + 32768);    // 24 KB  [4,3072]
  float* ssf = (float*)(ws + (88u << 20) + 65536);   // 256 KB [64,1024]
  float* ssc = (float*)(ws + (88u << 20) + 65536 + 262144);  // 256 B [64]

  prep_main<<<8192, 256, 0, stream>>>(fm, Wq, Wk, Wv, Wo, bq, bk, bv,
                                      wW, wWo, bC, x);
  scene_qkv<<<768, 256, 0, stream>>>(scene, wW, bC, sqv, qkv);
  // feature QKV: [4096,1024] @ [3072,1024]^T + bC -> qkv feature rows (REMAP)
  gemm_bt<1, 1><<<dim3(24, 32), 256, 0, stream>>>(x, wW, bC, qkv, nullptr,
                                                  4096, 3072, 1024);
  // x dead; per-key scene scores + fused rel prep (single 16MB rel read)
  sscomp<<<4100, 256, 0, stream>>>(qkv, sqv, ssf, ssc);
  prep_relr1<<<2048, 256, 0, stream>>>(rel, relf, lR1);
  flash_kernel<<<1024, 256, 0, stream>>>(qkv, relf, attn, lR1, ssf, ssc);
  // output projection: [8192,1024] @ [1024,1024]^T + bo -> f32 out
  gemm_bt<0, 0><<<dim3(8, 64), 256, 0, stream>>>(attn, wWo, bo, nullptr, out,
                                                 8192, 1024, 1024);
}

// Round 13
// 255.020 us; speedup vs baseline: 1.1235x; 1.1235x over previous
//
#include <hip/hip_runtime.h>
#include <hip/hip_bf16.h>
#include <cstdint>

// Problem constants: B=4, N=1024, F=1024, H=16, D=64, S=2N=2048.
typedef __hip_bfloat16 bf16;
typedef __attribute__((ext_vector_type(8))) short short8;   // 8 x bf16 (4 VGPRs)
typedef __attribute__((ext_vector_type(4))) short short4v;  // 4 x bf16
typedef __attribute__((ext_vector_type(4))) float f32x4;
typedef __attribute__((ext_vector_type(2))) unsigned int uint2v;

#define MFMA16(a, b, c) __builtin_amdgcn_mfma_f32_16x16x32_bf16((a), (b), (c), 0, 0, 0)

__device__ __forceinline__ void gl2lds16(const void* g, void* l) {
  __builtin_amdgcn_global_load_lds(
      (const __attribute__((address_space(1))) unsigned int*)g,
      (__attribute__((address_space(3))) unsigned int*)l,
      16, 0, 0);
}

// pack two f32 -> bf16x2 in ONE VALU op (RNE).
__device__ __forceinline__ unsigned int pkcvt(float a, float b) {
  unsigned int r;
  asm("v_cvt_pk_bf16_f32 %0, %1, %2" : "=v"(r) : "v"(a), "v"(b));
  return r;
}

__device__ __forceinline__ float b2f(unsigned short u) {
  union { unsigned u; float f; } x;
  x.u = ((unsigned)u) << 16;
  return x.f;
}

__device__ __forceinline__ uint2v plswap32(unsigned a, unsigned b) {
#if __has_builtin(__builtin_amdgcn_permlane32_swap)
  return __builtin_amdgcn_permlane32_swap(a, b, false, false);
#else
  const unsigned ax = __shfl_xor((int)a, 32), bx = __shfl_xor((int)b, 32);
  const bool hi = (threadIdx.x & 32) != 0;
  uint2v r;
  r[0] = hi ? bx : a;
  r[1] = hi ? b : ax;
  return r;
#endif
}

__device__ __forceinline__ uint2v plswap16(unsigned a, unsigned b) {
#if __has_builtin(__builtin_amdgcn_permlane16_swap)
  return __builtin_amdgcn_permlane16_swap(a, b, false, false);
#else
  const unsigned ax = __shfl_xor((int)a, 16), bx = __shfl_xor((int)b, 16);
  const bool hi = (threadIdx.x & 16) != 0;
  uint2v r;
  r[0] = hi ? bx : a;
  r[1] = hi ? b : ax;
  return r;
#endif
}

template <int V> struct IC { static constexpr int value = V; };

// ---------------------------------------------------------------------------
// v10 GEMM (best measured). BK=64, 128x128, 4 waves, both-sides XOR swizzle.
// REMAP=1: output row r (0..4095) -> qkv row (r>>10)*2048 + 1024 + (r&1023).
// ---------------------------------------------------------------------------
template <int WRITE_BF16, int REMAP>
__global__ __launch_bounds__(256) void gemm_bt(
    const bf16* __restrict__ A, const bf16* __restrict__ Bt,
    const float* __restrict__ bias, bf16* __restrict__ outb,
    float* __restrict__ outf, int M, int N, int K) {
  __shared__ bf16 sA[128 * 64];
  __shared__ bf16 sB[128 * 64];
  const int tid = threadIdx.x, w = tid >> 6, lane = tid & 63;
  const int n16 = lane & 15, quad = lane >> 4;
  const int mBase = blockIdx.y * 128, nBase = blockIdx.x * 128;
  const int wr = w >> 1, wc = w & 1;

  f32x4 acc[4][4];
#pragma unroll
  for (int mi = 0; mi < 4; mi++)
#pragma unroll
    for (int ni = 0; ni < 4; ni++) acc[mi][ni] = (f32x4){0.f, 0.f, 0.f, 0.f};

  const bf16* ag[4];
  const bf16* bg[4];
#pragma unroll
  for (int i = 0; i < 4; i++) {
    const int e = (i * 256 + tid) * 8;
    const int row = e >> 6, c0 = e & 63;
    const int col = c0 ^ ((row & 7) << 3);
    ag[i] = A + (size_t)(mBase + row) * K + col;
    bg[i] = Bt + (size_t)(nBase + row) * K + col;
  }
  const int u = (quad * 16) ^ ((n16 & 7) << 4);
  const int a0 = (wr * 64 + n16) * 128 + u;
  const int b0 = (wc * 64 + n16) * 128 + u;
  const char* const sAB = (const char*)sA;
  const char* const sBB = (const char*)sB;

  for (int k0 = 0; k0 < K; k0 += 64) {
    __syncthreads();
#pragma unroll
    for (int i = 0; i < 4; i++) {
      gl2lds16(ag[i] + k0, sA + i * 2048 + w * 512);
      gl2lds16(bg[i] + k0, sB + i * 2048 + w * 512);
    }
    __syncthreads();

#pragma unroll
    for (int kk = 0; kk < 2; kk++) {
      short8 af[4], bfg[4];
#pragma unroll
      for (int t = 0; t < 4; t++) {
        af[t] = *(const short8*)(sAB + (a0 ^ (kk << 6)) + t * 2048);
        bfg[t] = *(const short8*)(sBB + (b0 ^ (kk << 6)) + t * 2048);
      }
#pragma unroll
      for (int mi = 0; mi < 4; mi++)
#pragma unroll
        for (int ni = 0; ni < 4; ni++)
          acc[mi][ni] = MFMA16(af[mi], bfg[ni], acc[mi][ni]);
    }
  }

#pragma unroll
  for (int mi = 0; mi < 4; mi++)
#pragma unroll
    for (int ni = 0; ni < 4; ni++)
#pragma unroll
      for (int r = 0; r < 4; r++) {
        const int row = mBase + wr * 64 + mi * 16 + quad * 4 + r;
        const int col = nBase + wc * 64 + ni * 16 + n16;
        const size_t orow =
            REMAP ? (size_t)((row >> 10) * 2048 + 1024 + (row & 1023))
                  : (size_t)row;
        const float v = acc[mi][ni][r] + bias[col];
        if (WRITE_BF16)
          outb[orow * N + col] = __float2bfloat16(v);
        else
          outf[orow * N + col] = v;
      }
}

// ---------------------------------------------------------------------------
// v17: flash split into two specialized kernels (v16's dual-path union cost
// 136 VGPR -> 3-wave tier + divergent body; occupancy stuck ~11%).
// flash_feat: feature-q blocks only (512) — v16 feature path verbatim.
// flash_scene: scene-q blocks only (512) — no Q frags, no sK, no QK^T.
// Identical math; disjoint attn rows.
// ---------------------------------------------------------------------------
__global__ __launch_bounds__(256) void flash_feat(
    const bf16* __restrict__ qkv, const float* __restrict__ relf,
    bf16* __restrict__ attn, const float* __restrict__ lR1) {
  constexpr int S = 2048, R3 = 3072;
  __shared__ __align__(16) char smem[32768];
  bf16* const sK = (bf16*)smem;       // [buf][key][64] 128 B rows, XOR-swizzled
  char* const sVtB = smem + 16384;    // [buf][d][key] 128 B rows, XOR-swizzled

  const int tid = threadIdx.x, w = tid >> 6, lane = tid & 63;
  const int n16 = lane & 15, quad = lane >> 4;
  const int bh = blockIdx.x >> 3;
  const int qt = 8 + (blockIdx.x & 7);
  const int h = bh & 15, b = bh >> 4;
  const int qb = qt * 128 + w * 32;
  const size_t rowbase = (size_t)b * S;
  const size_t krow0 = rowbase + 1024;
  const float SC = 0.125f * 1.44269504f;
  const size_t TADV = (size_t)64 * R3;

  short8 qf[2][2];
#pragma unroll
  for (int mi = 0; mi < 2; mi++) {
    const bf16* qp = qkv + (rowbase + qb + mi * 16 + n16) * R3 + h * 64;
#pragma unroll
    for (int c = 0; c < 2; c++)
      qf[mi][c] = *(const short8*)(qp + c * 32 + quad * 8);
  }

  f32x4 ot[4][2];
#pragma unroll
  for (int nc = 0; nc < 4; nc++)
#pragma unroll
    for (int mi = 0; mi < 2; mi++) ot[nc][mi] = (f32x4){0.f, 0.f, 0.f, 0.f};
  float l_lane[2] = {0.f, 0.f};

  const bf16* kg0;
  const bf16* kg1;
  {
    const int e0 = tid * 8;
    const int e1i = (256 + tid) * 8;
    const int k0r = e0 >> 6, c00 = e0 & 63;
    const int k1r = e1i >> 6, c01 = e1i & 63;
    kg0 = qkv + (krow0 + k0r) * R3 + 1024 + h * 64 + (c00 ^ ((k0r & 7) << 3));
    kg1 = qkv + (krow0 + k1r) * R3 + 1024 + h * 64 + (c01 ^ ((k1r & 7) << 3));
  }
  const int kldsoff = w * 512;

  const int kb0 = n16 * 128 + ((quad * 16) ^ ((n16 & 7) << 4));
  const int kb1 = kb0 ^ 64;
  const char* const sKB = (const char*)sK;

  const int kp = lane & 31;
  const int vd0 = w * 16 + (lane >> 5) * 8;
  const int kp4 = kp * 4;
  const bf16* vp = qkv + (krow0 + 2 * kp) * R3 + 2048 + h * 64 + vd0;

  const int vb0 = 128 * n16 + ((16 * quad) ^ ((n16 & 7) << 4));
  const int vb1 = vb0 ^ 64;

  short8 v0, v1;
  auto vstage = [&](int bufbyte) {
    const unsigned* a1 = (const unsigned*)&v1;
    const unsigned* a0 = (const unsigned*)&v0;
#pragma unroll
    for (int j = 0; j < 4; j++) {
      const unsigned lo = __builtin_amdgcn_perm(a1[j], a0[j], 0x05040100u);
      const unsigned hi = __builtin_amdgcn_perm(a1[j], a0[j], 0x07060302u);
      *(unsigned*)(sVtB + bufbyte + 128 * (vd0 + 2 * j) + (kp4 ^ ((2 * j) << 4))) = lo;
      *(unsigned*)(sVtB + bufbyte + 128 * (vd0 + 2 * j + 1) + (kp4 ^ ((2 * j + 1) << 4))) = hi;
    }
  };

  gl2lds16(kg0, sK + kldsoff);
  gl2lds16(kg1, sK + kldsoff + 2048);
  kg0 += TADV;
  kg1 += TADV;

  v0 = *(const short8*)vp;
  v1 = *(const short8*)(vp + R3);
  vstage(0);
  vp += TADV;
  v0 = *(const short8*)vp;
  v1 = *(const short8*)(vp + R3);
  vp += TADV;

  float4 rv[8];
  const float4* rpA = (const float4*)relf +
                      (size_t)(qt * 32 + 16) * 2048 + w * 512 + lane;
  const float4* rpB = rpA + 256;
#pragma unroll
  for (int j = 0; j < 4; j++) {
    rv[j] = rpA[j * 64];
    rv[4 + j] = rpB[j * 64];
  }
  rpA += 2048;
  rpB += 2048;

  auto step = [&](auto curc, bool dodma, bool dovpf) {
    constexpr int CUR = decltype(curc)::value;
    constexpr int NXT = CUR ^ 1;
    __syncthreads();

    if (dodma) {
      gl2lds16(kg0, sK + NXT * 4096 + kldsoff);
      kg0 += TADV;
      gl2lds16(kg1, sK + NXT * 4096 + kldsoff + 2048);
      kg1 += TADV;
      vstage(NXT * 8192);
    }

#pragma unroll
    for (int kc = 0; kc < 2; kc++) {
      f32x4 st[2][2];
#pragma unroll
      for (int t2 = 0; t2 < 2; t2++) {
        const int kt4 = 2 * kc + t2;
        short8 kf[2];
        kf[0] = *(const short8*)(sKB + CUR * 8192 + kt4 * 2048 + kb0);
        kf[1] = *(const short8*)(sKB + CUR * 8192 + kt4 * 2048 + kb1);
#pragma unroll
        for (int mi = 0; mi < 2; mi++) {
          f32x4 z = (f32x4){0.f, 0.f, 0.f, 0.f};
          z = MFMA16(kf[0], qf[mi][0], z);
          z = MFMA16(kf[1], qf[mi][1], z);
          st[t2][mi] = z;
        }
      }
      if (kc == 0 && dovpf) {
        v0 = *(const short8*)vp;
        v1 = *(const short8*)(vp + R3);
        vp += TADV;
      }
      short8 pb[2];
#pragma unroll
      for (int mi = 0; mi < 2; mi++) {
        float acc = 0.f;
        unsigned d[2][2];
#pragma unroll
        for (int t2 = 0; t2 < 2; t2++) {
          const float4 rr = rv[mi * 4 + 2 * kc + t2];
          float p0 = __builtin_amdgcn_exp2f(fmaf(st[t2][mi][0], SC, rr.x));
          float p1 = __builtin_amdgcn_exp2f(fmaf(st[t2][mi][1], SC, rr.y));
          float p2 = __builtin_amdgcn_exp2f(fmaf(st[t2][mi][2], SC, rr.z));
          float p3 = __builtin_amdgcn_exp2f(fmaf(st[t2][mi][3], SC, rr.w));
          acc += (p0 + p1) + (p2 + p3);
          d[t2][0] = pkcvt(p0, p1);
          d[t2][1] = pkcvt(p2, p3);
        }
        l_lane[mi] += acc;
        const uint2v e0 = plswap32(d[0][0], d[1][0]);
        const uint2v e1 = plswap32(d[0][1], d[1][1]);
        const uint2v f0 = plswap16(e0[0], e0[1]);
        const uint2v f1 = plswap16(e1[0], e1[1]);
        union { short8 s; unsigned u[4]; } P;
        P.u[0] = f0[0]; P.u[1] = f1[0]; P.u[2] = f0[1]; P.u[3] = f1[1];
        pb[mi] = P.s;
      }
      if (kc == 1 && dodma) {
#pragma unroll
        for (int j = 0; j < 4; j++) {
          rv[j] = rpA[j * 64];
          rv[4 + j] = rpB[j * 64];
        }
        rpA += 2048;
        rpB += 2048;
      }
      short8 va[4];
#pragma unroll
      for (int nc = 0; nc < 4; nc++)
        va[nc] = *(const short8*)(sVtB + CUR * 8192 + 2048 * nc +
                                  (kc ? vb1 : vb0));
#pragma unroll
      for (int nc = 0; nc < 4; nc++)
#pragma unroll
        for (int mi = 0; mi < 2; mi++)
          ot[nc][mi] = MFMA16(va[nc], pb[mi], ot[nc][mi]);
    }
  };

#pragma unroll 1
  for (int t = 0; t < 8; t++) {
    const bool g = (t < 7);
    step(IC<0>{}, true, g);
    step(IC<1>{}, g, g);
  }

  // ---- scene-key collapse correction (exact, f32)
  {
    const bf16* kscp = qkv + rowbase * R3 + 1024 + h * 64 + quad * 8;
    const short8 ks0 = *(const short8*)(kscp);
    const short8 ks1 = *(const short8*)(kscp + 32);
    float e1v[2];
#pragma unroll
    for (int mi = 0; mi < 2; mi++) {
      float ss = 0.f;
#pragma unroll
      for (int j = 0; j < 8; j++) {
        ss = fmaf(b2f((unsigned short)qf[mi][0][j]), b2f((unsigned short)ks0[j]), ss);
        ss = fmaf(b2f((unsigned short)qf[mi][1][j]), b2f((unsigned short)ks1[j]), ss);
      }
      ss += __shfl_xor(ss, 16);
      ss += __shfl_xor(ss, 32);
      const float lr = lR1[qb + mi * 16 + n16];
      e1v[mi] = __builtin_amdgcn_exp2f(fmaf(ss, SC, lr));
      if (quad == 0) l_lane[mi] += e1v[mi];
    }
    const bf16* vscp = qkv + rowbase * R3 + 2048 + h * 64;
#pragma unroll
    for (int nc = 0; nc < 4; nc++) {
      const int d0 = nc * 16 + quad * 4;
      const uint2 vv = *(const uint2*)(vscp + d0);
      const float w0 = b2f((unsigned short)(vv.x & 0xffff));
      const float w1 = b2f((unsigned short)(vv.x >> 16));
      const float w2 = b2f((unsigned short)(vv.y & 0xffff));
      const float w3 = b2f((unsigned short)(vv.y >> 16));
#pragma unroll
      for (int mi = 0; mi < 2; mi++) {
        ot[nc][mi][0] = fmaf(e1v[mi], w0, ot[nc][mi][0]);
        ot[nc][mi][1] = fmaf(e1v[mi], w1, ot[nc][mi][1]);
        ot[nc][mi][2] = fmaf(e1v[mi], w2, ot[nc][mi][2]);
        ot[nc][mi][3] = fmaf(e1v[mi], w3, ot[nc][mi][3]);
      }
    }
  }

  float inv[2];
#pragma unroll
  for (int mi = 0; mi < 2; mi++) {
    float l = l_lane[mi];
    l += __shfl_xor(l, 16);
    l += __shfl_xor(l, 32);
    inv[mi] = 1.0f / l;
  }
  __syncthreads();
  bf16* const sEp = (bf16*)smem + w * (32 * 72);
#pragma unroll
  for (int mi = 0; mi < 2; mi++)
#pragma unroll
    for (int nc = 0; nc < 4; nc++) {
      uint2 pk;
      pk.x = pkcvt(ot[nc][mi][0] * inv[mi], ot[nc][mi][1] * inv[mi]);
      pk.y = pkcvt(ot[nc][mi][2] * inv[mi], ot[nc][mi][3] * inv[mi]);
      *(uint2*)(&sEp[(mi * 16 + n16) * 72 + nc * 16 + quad * 4]) = pk;
    }
#pragma unroll
  for (int t = 0; t < 4; t++) {
    const int row = t * 8 + (lane >> 3);
    const int dcol = (lane & 7) * 8;
    const short8 vrow = *(const short8*)(&sEp[row * 72 + dcol]);
    *(short8*)(attn + (rowbase + qb + row) * 1024 + h * 64 + dcol) = vrow;
  }
}

// Scene-query flash: no Q frags, no K staging, no QK^T. p = 2^(ssf[k]+rel').
__global__ __launch_bounds__(256) void flash_scene(
    const bf16* __restrict__ qkv, const float* __restrict__ relf,
    bf16* __restrict__ attn, const float* __restrict__ lR1,
    const float* __restrict__ ssf, const float* __restrict__ ssc) {
  constexpr int S = 2048, R3 = 3072;
  __shared__ __align__(16) char smem[18432];  // sVt 16384 + epilogue reuse
  char* const sVtB = smem;

  const int tid = threadIdx.x, w = tid >> 6, lane = tid & 63;
  const int n16 = lane & 15, quad = lane >> 4;
  const int bh = blockIdx.x >> 3;
  const int qt = blockIdx.x & 7;
  const int h = bh & 15, b = bh >> 4;
  const int qb = qt * 128 + w * 32;
  const size_t rowbase = (size_t)b * S;
  const size_t krow0 = rowbase + 1024;
  const size_t TADV = (size_t)64 * R3;

  f32x4 ot[4][2];
#pragma unroll
  for (int nc = 0; nc < 4; nc++)
#pragma unroll
    for (int mi = 0; mi < 2; mi++) ot[nc][mi] = (f32x4){0.f, 0.f, 0.f, 0.f};
  float l_lane[2] = {0.f, 0.f};

  const int kp = lane & 31;
  const int vd0 = w * 16 + (lane >> 5) * 8;
  const int kp4 = kp * 4;
  const bf16* vp = qkv + (krow0 + 2 * kp) * R3 + 2048 + h * 64 + vd0;

  const int vb0 = 128 * n16 + ((16 * quad) ^ ((n16 & 7) << 4));
  const int vb1 = vb0 ^ 64;

  const float* ssp = ssf + (size_t)bh * 1024 + quad * 4;

  short8 v0, v1;
  auto vstage = [&](int bufbyte) {
    const unsigned* a1 = (const unsigned*)&v1;
    const unsigned* a0 = (const unsigned*)&v0;
#pragma unroll
    for (int j = 0; j < 4; j++) {
      const unsigned lo = __builtin_amdgcn_perm(a1[j], a0[j], 0x05040100u);
      const unsigned hi = __builtin_amdgcn_perm(a1[j], a0[j], 0x07060302u);
      *(unsigned*)(sVtB + bufbyte + 128 * (vd0 + 2 * j) + (kp4 ^ ((2 * j) << 4))) = lo;
      *(unsigned*)(sVtB + bufbyte + 128 * (vd0 + 2 * j + 1) + (kp4 ^ ((2 * j + 1) << 4))) = hi;
    }
  };

  v0 = *(const short8*)vp;
  v1 = *(const short8*)(vp + R3);
  vstage(0);
  vp += TADV;
  v0 = *(const short8*)vp;
  v1 = *(const short8*)(vp + R3);
  vp += TADV;

  float4 rv[8];
  const float4* rpA = (const float4*)relf +
                      (size_t)(qt * 32 + 16) * 2048 + w * 512 + lane;
  const float4* rpB = rpA + 256;
#pragma unroll
  for (int j = 0; j < 4; j++) {
    rv[j] = rpA[j * 64];
    rv[4 + j] = rpB[j * 64];
  }
  rpA += 2048;
  rpB += 2048;

  auto step = [&](auto curc, bool dodma, bool dovpf) {
    constexpr int CUR = decltype(curc)::value;
    constexpr int NXT = CUR ^ 1;
    __syncthreads();
    if (dodma) vstage(NXT * 8192);

#pragma unroll
    for (int kc = 0; kc < 2; kc++) {
      float4 ssq[2];
      ssq[0] = *(const float4*)(ssp + (2 * kc + 0) * 16);
      ssq[1] = *(const float4*)(ssp + (2 * kc + 1) * 16);
      if (kc == 0 && dovpf) {
        v0 = *(const short8*)vp;
        v1 = *(const short8*)(vp + R3);
        vp += TADV;
      }
      short8 pb[2];
#pragma unroll
      for (int mi = 0; mi < 2; mi++) {
        float acc = 0.f;
        unsigned d[2][2];
#pragma unroll
        for (int t2 = 0; t2 < 2; t2++) {
          const float4 rr = rv[mi * 4 + 2 * kc + t2];
          float p0 = __builtin_amdgcn_exp2f(ssq[t2].x + rr.x);
          float p1 = __builtin_amdgcn_exp2f(ssq[t2].y + rr.y);
          float p2 = __builtin_amdgcn_exp2f(ssq[t2].z + rr.z);
          float p3 = __builtin_amdgcn_exp2f(ssq[t2].w + rr.w);
          acc += (p0 + p1) + (p2 + p3);
          d[t2][0] = pkcvt(p0, p1);
          d[t2][1] = pkcvt(p2, p3);
        }
        l_lane[mi] += acc;
        const uint2v e0 = plswap32(d[0][0], d[1][0]);
        const uint2v e1 = plswap32(d[0][1], d[1][1]);
        const uint2v f0 = plswap16(e0[0], e0[1]);
        const uint2v f1 = plswap16(e1[0], e1[1]);
        union { short8 s; unsigned u[4]; } P;
        P.u[0] = f0[0]; P.u[1] = f1[0]; P.u[2] = f0[1]; P.u[3] = f1[1];
        pb[mi] = P.s;
      }
      if (kc == 1 && dodma) {
#pragma unroll
        for (int j = 0; j < 4; j++) {
          rv[j] = rpA[j * 64];
          rv[4 + j] = rpB[j * 64];
        }
        rpA += 2048;
        rpB += 2048;
      }
      short8 va[4];
#pragma unroll
      for (int nc = 0; nc < 4; nc++)
        va[nc] = *(const short8*)(sVtB + CUR * 8192 + 2048 * nc +
                                  (kc ? vb1 : vb0));
#pragma unroll
      for (int nc = 0; nc < 4; nc++)
#pragma unroll
        for (int mi = 0; mi < 2; mi++)
          ot[nc][mi] = MFMA16(va[nc], pb[mi], ot[nc][mi]);
    }
    ssp += 64;
  };

#pragma unroll 1
  for (int t = 0; t < 8; t++) {
    const bool g = (t < 7);
    step(IC<0>{}, true, g);
    step(IC<1>{}, g, g);
  }

  // ---- scene-key collapse correction (scalar ssc)
  {
    const float sscv = ssc[bh];
    float e1v[2];
#pragma unroll
    for (int mi = 0; mi < 2; mi++) {
      const float lr = lR1[qb + mi * 16 + n16];
      e1v[mi] = __builtin_amdgcn_exp2f(sscv + lr);
      if (quad == 0) l_lane[mi] += e1v[mi];
    }
    const bf16* vscp = qkv + rowbase * R3 + 2048 + h * 64;
#pragma unroll
    for (int nc = 0; nc < 4; nc++) {
      const int d0 = nc * 16 + quad * 4;
      const uint2 vv = *(const uint2*)(vscp + d0);
      const float w0 = b2f((unsigned short)(vv.x & 0xffff));
      const float w1 = b2f((unsigned short)(vv.x >> 16));
      const float w2 = b2f((unsigned short)(vv.y & 0xffff));
      const float w3 = b2f((unsigned short)(vv.y >> 16));
#pragma unroll
      for (int mi = 0; mi < 2; mi++) {
        ot[nc][mi][0] = fmaf(e1v[mi], w0, ot[nc][mi][0]);
        ot[nc][mi][1] = fmaf(e1v[mi], w1, ot[nc][mi][1]);
        ot[nc][mi][2] = fmaf(e1v[mi], w2, ot[nc][mi][2]);
        ot[nc][mi][3] = fmaf(e1v[mi], w3, ot[nc][mi][3]);
      }
    }
  }

  float inv[2];
#pragma unroll
  for (int mi = 0; mi < 2; mi++) {
    float l = l_lane[mi];
    l += __shfl_xor(l, 16);
    l += __shfl_xor(l, 32);
    inv[mi] = 1.0f / l;
  }
  __syncthreads();
  bf16* const sEp = (bf16*)smem + w * (32 * 72);
#pragma unroll
  for (int mi = 0; mi < 2; mi++)
#pragma unroll
    for (int nc = 0; nc < 4; nc++) {
      uint2 pk;
      pk.x = pkcvt(ot[nc][mi][0] * inv[mi], ot[nc][mi][1] * inv[mi]);
      pk.y = pkcvt(ot[nc][mi][2] * inv[mi], ot[nc][mi][3] * inv[mi]);
      *(uint2*)(&sEp[(mi * 16 + n16) * 72 + nc * 16 + quad * 4]) = pk;
    }
#pragma unroll
  for (int t = 0; t < 4; t++) {
    const int row = t * 8 + (lane >> 3);
    const int dcol = (lane & 7) * 8;
    const short8 vrow = *(const short8*)(&sEp[row * 72 + dcol]);
    *(short8*)(attn + (rowbase + qb + row) * 1024 + h * 64 + dcol) = vrow;
  }
}

// ---------------------------------------------------------------------------
// prep: weight cast + bias concat + xF build (FEATURE rows only: 4096x1024)
// ---------------------------------------------------------------------------
__global__ void prep_main(const float* __restrict__ fm, const float* __restrict__ Wq,
                          const float* __restrict__ Wk, const float* __restrict__ Wv,
                          const float* __restrict__ Wo, const float* __restrict__ bq,
                          const float* __restrict__ bk, const float* __restrict__ bv,
                          bf16* __restrict__ wW, bf16* __restrict__ wWo,
                          float* __restrict__ bC, bf16* __restrict__ x) {
  const int blk = blockIdx.x;
  if (blk < 4096) {
    const int sel = blk >> 10;
    const int i = (((blk & 1023) * 256) + threadIdx.x) * 4;
    const float* src = (sel == 0) ? Wq : (sel == 1) ? Wk : (sel == 2) ? Wv : Wo;
    bf16* dst = (sel < 3) ? (wW + ((size_t)sel << 20) + i) : (wWo + i);
    const float4 v = *(const float4*)(src + i);
    dst[0] = __float2bfloat16(v.x);
    dst[1] = __float2bfloat16(v.y);
    dst[2] = __float2bfloat16(v.z);
    dst[3] = __float2bfloat16(v.w);
    if (blk == 0) {
      for (int z = threadIdx.x; z < 3072; z += 256)
        bC[z] = (z < 1024) ? bq[z] : (z < 2048) ? bk[z - 1024] : bv[z - 2048];
    }
  } else {
    const size_t i = ((size_t)(blk - 4096) * 256 + threadIdx.x) * 4;
    const float4 v = *(const float4*)(fm + i);
    bf16* d = x + i;
    d[0] = __float2bfloat16(v.x);
    d[1] = __float2bfloat16(v.y);
    d[2] = __float2bfloat16(v.z);
    d[3] = __float2bfloat16(v.w);
  }
}

// scene QKV: sqv[b][j] = bf16( bC[j] + sum_d bf16(scene[b][d]) * wW[j][d] )
// ALSO writes scene row 0 of qkv (k_scene / v_scene for the corrections).
__global__ void scene_qkv(const float* __restrict__ scene,
                          const bf16* __restrict__ wW,
                          const float* __restrict__ bC, bf16* __restrict__ sqv,
                          bf16* __restrict__ qkv) {
  const int tid = threadIdx.x;
  const int p = blockIdx.x * 16 + (tid >> 4);  // 0..12287
  const int i16 = tid & 15;
  const int b = p / 3072, j = p % 3072;
  const bf16* wr = wW + (size_t)j * 1024 + i16 * 64;
  const float* sr = scene + (size_t)b * 1024 + i16 * 64;
  float s = 0.f;
#pragma unroll
  for (int t = 0; t < 8; t++) {
    const short8 wv = *(const short8*)(wr + t * 8);
    const float4 x0 = *(const float4*)(sr + t * 8);
    const float4 x1 = *(const float4*)(sr + t * 8 + 4);
    const float xs[8] = {x0.x, x0.y, x0.z, x0.w, x1.x, x1.y, x1.z, x1.w};
#pragma unroll
    for (int e = 0; e < 8; e++) {
      const float xb = __bfloat162float(__float2bfloat16(xs[e]));
      s = fmaf(b2f((unsigned short)wv[e]), xb, s);
    }
  }
  s += __shfl_xor(s, 1);
  s += __shfl_xor(s, 2);
  s += __shfl_xor(s, 4);
  s += __shfl_xor(s, 8);
  if (i16 == 0) {
    const bf16 val = __float2bfloat16(s + bC[j]);
    sqv[(size_t)b * 3072 + j] = val;
    qkv[(size_t)b * 2048 * 3072 + j] = val;  // scene row 0 of batch b
  }
}

// ssf[bh][k] = SC * dot(q_scene[b,h], K_feat[b,h,k])  (k<1024), and
// ss_sc[bh] = SC * dot(q_scene, k_scene). 16 lanes per dot, 4 d's per lane.
__global__ void sscomp(const bf16* __restrict__ qkv, const bf16* __restrict__ sqv,
                       float* __restrict__ ssf, float* __restrict__ ss_sc) {
  const int tid = threadIdx.x;
  const int g = blockIdx.x * 16 + (tid >> 4);  // 0..65599
  const int i16 = tid & 15;
  const float SC = 0.125f * 1.44269504f;
  const bf16* kr;
  const bf16* qr;
  int bh;
  if (g < 65536) {
    bh = g >> 10;
    const int k = g & 1023;
    const int b = bh >> 4, h = bh & 15;
    kr = qkv + ((size_t)(b * 2048 + 1024 + k)) * 3072 + 1024 + h * 64 + i16 * 4;
    qr = sqv + (size_t)b * 3072 + h * 64 + i16 * 4;
  } else {
    bh = g - 65536;  // 0..63
    const int b = bh >> 4, h = bh & 15;
    kr = sqv + (size_t)b * 3072 + 1024 + h * 64 + i16 * 4;
    qr = sqv + (size_t)b * 3072 + h * 64 + i16 * 4;
  }
  const short4v kv = *(const short4v*)kr;
  const short4v qv = *(const short4v*)qr;
  float s = 0.f;
#pragma unroll
  for (int e = 0; e < 4; e++)
    s = fmaf(b2f((unsigned short)kv[e]), b2f((unsigned short)qv[e]), s);
  s += __shfl_xor(s, 1);
  s += __shfl_xor(s, 2);
  s += __shfl_xor(s, 4);
  s += __shfl_xor(s, 8);
  if (i16 == 0) {
    if (g < 65536) ssf[g] = s * SC;
    else ss_sc[bh] = s * SC;
  }
}

// Fused rel prep: one block per q row (0..2047). Reads the row ONCE:
//   scene half (k<1024)   -> lR1[q] = log2 sum e^rel
//   feature half (k>=1024)-> relf fragment-ordered (x log2e)
__global__ void prep_relr1(const float* __restrict__ rel, float* __restrict__ relf,
                           float* __restrict__ lR1) {
  __shared__ float red[4];
  const int q = blockIdx.x;
  const int t = threadIdx.x;
  const float L2E = 1.44269504f;
  const float4 vs = *(const float4*)(rel + (size_t)q * 2048 + t * 4);
  float s = __builtin_amdgcn_exp2f(vs.x * L2E) + __builtin_amdgcn_exp2f(vs.y * L2E) +
            __builtin_amdgcn_exp2f(vs.z * L2E) + __builtin_amdgcn_exp2f(vs.w * L2E);
  s += __shfl_xor(s, 1);
  s += __shfl_xor(s, 2);
  s += __shfl_xor(s, 4);
  s += __shfl_xor(s, 8);
  s += __shfl_xor(s, 16);
  s += __shfl_xor(s, 32);
  if ((t & 63) == 0) red[t >> 6] = s;
  const int ktL = t >> 4;             // 0..15
  const int sfr = t & 15;
  const int kt4 = sfr >> 2, quad = sfr & 3;
  const int key = 1024 + ktL * 64 + kt4 * 16 + quad * 4;
  float4 vf = *(const float4*)(rel + (size_t)q * 2048 + key);
  vf.x *= L2E; vf.y *= L2E; vf.z *= L2E; vf.w *= L2E;
  const int qt = q >> 7, w = (q >> 5) & 3, mi = (q >> 4) & 1, n16 = q & 15;
  const int widx = (qt << 16) + ((16 + ktL) << 11) + (w << 9) +
                   ((mi * 4 + kt4) << 6) + (quad * 16 + n16);
  ((float4*)relf)[widx] = vf;
  __syncthreads();
  if (t == 0)
    lR1[q] = __builtin_amdgcn_logf((red[0] + red[1]) + (red[2] + red[3]));
}

// ---------------------------------------------------------------------------
extern "C" void kernel_launch(void* const* d_in, const int* in_sizes, int n_in,
                              void* d_out, int out_size, void* d_ws,
                              size_t ws_size, hipStream_t stream) {
  const float* fm    = (const float*)d_in[0];
  const float* scene = (const float*)d_in[1];
  const float* rel   = (const float*)d_in[2];
  const float* Wq    = (const float*)d_in[3];
  const float* bq    = (const float*)d_in[4];
  const float* Wk    = (const float*)d_in[5];
  const float* bk    = (const float*)d_in[6];
  const float* Wv    = (const float*)d_in[7];
  const float* bv    = (const float*)d_in[8];
  const float* Wo    = (const float*)d_in[9];
  const float* bo    = (const float*)d_in[10];
  float* out = (float*)d_out;

  char* ws = (char*)d_ws;
  bf16* x    = (bf16*)(ws);                          // 8 MB   [4096,1024] feature rows
  float* relf = (float*)(ws);                        // 16 MB  (aliases x; x dead after QKV)
  bf16* qkv  = (bf16*)(ws + (16u << 20));            // 48 MB  [8192,3072]
  bf16* attn = (bf16*)(ws + (64u << 20));            // 16 MB  [8192,1024]
  bf16* wW   = (bf16*)(ws + (80u << 20));            // 6 MB   [3072,1024]
  bf16* wWo  = (bf16*)(ws + (86u << 20));            // 2 MB   [1024,1024]
  float* bC  = (float*)(ws + (88u << 20));           // 12 KB
  float* lR1 = (float*)(ws + (88u << 20) + 16384);   // 8 KB   [2048]
  bf16* sqv  = (bf16*)(ws + (88u << 20) + 32768);    // 24 KB  [4,3072]
  float* ssf = (float*)(ws + (88u << 20) + 65536);   // 256 KB [64,1024]
  float* ssc = (float*)(ws + (88u << 20) + 65536 + 262144);  // 256 B [64]

  prep_main<<<8192, 256, 0, stream>>>(fm, Wq, Wk, Wv, Wo, bq, bk, bv,
                                      wW, wWo, bC, x);
  scene_qkv<<<768, 256, 0, stream>>>(scene, wW, bC, sqv, qkv);
  // feature QKV: [4096,1024] @ [3072,1024]^T + bC -> qkv feature rows (REMAP)
  gemm_bt<1, 1><<<dim3(24, 32), 256, 0, stream>>>(x, wW, bC, qkv, nullptr,
                                                  4096, 3072, 1024);
  // x dead; per-key scene scores + fused rel prep (single 16MB rel read)
  sscomp<<<4100, 256, 0, stream>>>(qkv, sqv, ssf, ssc);
  prep_relr1<<<2048, 256, 0, stream>>>(rel, relf, lR1);
  // attention, split by query class (independent: disjoint attn rows)
  flash_feat<<<512, 256, 0, stream>>>(qkv, relf, attn, lR1);
  flash_scene<<<512, 256, 0, stream>>>(qkv, relf, attn, lR1, ssf, ssc);
  // output projection: [8192,1024] @ [1024,1024]^T + bo -> f32 out
  gemm_bt<0, 0><<<dim3(8, 64), 256, 0, stream>>>(attn, wWo, bo, nullptr, out,
                                                 8192, 1024, 1024);
}